// Round 8
// baseline (1403.076 us; speedup 1.0000x reference)
//
#include <hip/hip_runtime.h>

#define NN 50000
#define NE 300000
#define EMB 256
#define HID 512
#define NL 5

typedef __attribute__((ext_vector_type(8))) short bf16x8;
typedef __attribute__((ext_vector_type(4))) float f32x4;
typedef __attribute__((ext_vector_type(8))) unsigned short u16x8;
typedef __attribute__((ext_vector_type(4))) unsigned short u16x4;

union U8u { u16x8 v; bf16x8 b; unsigned short s[8]; };

__device__ __forceinline__ float bf2f(unsigned short u) {
  union { unsigned int i; float f; } c; c.i = ((unsigned int)u) << 16; return c.f;
}
__device__ __forceinline__ unsigned short f2bf(float f) {
  union { float f; unsigned int i; } c; c.f = f;
  unsigned int r = c.i + 0x7FFF + ((c.i >> 16) & 1);
  return (unsigned short)(r >> 16);
}

// ---------------- node encoder ----------------
__global__ __launch_bounds__(256) void k_init_h(const int* __restrict__ ids,
    const int* __restrict__ depth, const float* __restrict__ temb,
    const float* __restrict__ demb, float* __restrict__ h) {
  int gid = blockIdx.x * 256 + threadIdx.x;
  int row = gid >> 6;
  if (row >= NN) return;
  int c4 = (gid & 63) << 2;
  int id = ids[row];
  int d = depth[row]; d = d < 0 ? 0 : (d > 20 ? 20 : d);
  float4 a = *(const float4*)&temb[id * EMB + c4];
  float4 b = *(const float4*)&demb[d * EMB + c4];
  *(float4*)&h[row * EMB + c4] = make_float4(a.x + b.x, a.y + b.y, a.z + b.z, a.w + b.w);
}

// ---------------- CSR build ----------------
__global__ __launch_bounds__(256) void k_count(const int* __restrict__ dst, int* __restrict__ deg) {
  int e = blockIdx.x * 256 + threadIdx.x;
  if (e < NE) atomicAdd(&deg[dst[e]], 1);
}
__global__ __launch_bounds__(256) void k_scan1(const int* __restrict__ deg,
    int* __restrict__ row_off, int* __restrict__ bsums) {
  __shared__ int lds[256];
  int b = blockIdx.x, t = threadIdx.x;
  int base = b * 1024;
  int v[4]; int s = 0;
  for (int i = 0; i < 4; ++i) {
    int idx = base + t * 4 + i;
    v[i] = (idx < NN) ? deg[idx] : 0;
    s += v[i];
  }
  lds[t] = s; __syncthreads();
  for (int off = 1; off < 256; off <<= 1) {
    int x = (t >= off) ? lds[t - off] : 0; __syncthreads();
    lds[t] += x; __syncthreads();
  }
  int run = (t > 0) ? lds[t - 1] : 0;
  if (t == 255) bsums[b] = lds[255];
  for (int i = 0; i < 4; ++i) {
    int idx = base + t * 4 + i;
    if (idx < NN) row_off[idx] = run;
    run += v[i];
  }
}
__global__ __launch_bounds__(256) void k_scan2(int* __restrict__ bsums, int nb) {
  __shared__ int lds[256];
  int t = threadIdx.x;
  int v = (t < nb) ? bsums[t] : 0;
  lds[t] = v; __syncthreads();
  for (int off = 1; off < 256; off <<= 1) {
    int x = (t >= off) ? lds[t - off] : 0; __syncthreads();
    lds[t] += x; __syncthreads();
  }
  if (t < nb) bsums[t] = (t > 0) ? lds[t - 1] : 0;
}
__global__ __launch_bounds__(256) void k_scan3(int* __restrict__ row_off, const int* __restrict__ bsums) {
  int b = blockIdx.x, t = threadIdx.x;
  int base = b * 1024;
  int add = bsums[b];
  for (int i = 0; i < 4; ++i) {
    int idx = base + t * 4 + i;
    if (idx < NN) row_off[idx] += add;
  }
  if (b == 0 && t == 0) row_off[NN] = NE;
}
__global__ __launch_bounds__(256) void k_copy(const int* __restrict__ a, int* __restrict__ b) {
  int i = blockIdx.x * 256 + threadIdx.x;
  if (i < NN) b[i] = a[i];
}
__global__ __launch_bounds__(256) void k_fill(const int* __restrict__ src, const int* __restrict__ dst,
    const float* __restrict__ attr, int* __restrict__ cursor,
    int* __restrict__ ssrc, float2* __restrict__ sattr) {
  int e = blockIdx.x * 256 + threadIdx.x;
  if (e >= NE) return;
  int d = dst[e];
  int p = atomicAdd(&cursor[d], 1);
  ssrc[p] = src[e];
  sattr[p] = make_float2(attr[2 * e], attr[2 * e + 1]);
}

// ---------------- weight transpose + bf16 convert: W[R][C] -> Wt[C][R] ----------------
__global__ __launch_bounds__(256) void k_convW(const float* __restrict__ W,
    unsigned short* __restrict__ Wt, int R, int C) {
  __shared__ float t[32][33];
  int l = blockIdx.z;
  const float* Wl = W + (size_t)l * R * C;
  unsigned short* Wtl = Wt + (size_t)l * R * C;
  int c0 = blockIdx.x * 32, r0 = blockIdx.y * 32;
  int tx = threadIdx.x & 31, ty = threadIdx.x >> 5;  // ty 0..7
  for (int i = 0; i < 32; i += 8)
    t[ty + i][tx] = Wl[(size_t)(r0 + ty + i) * C + c0 + tx];
  __syncthreads();
  for (int i = 0; i < 32; i += 8)
    Wtl[(size_t)(c0 + ty + i) * R + r0 + tx] = f2bf(t[tx][ty + i]);
}

// ---------------- per-layer aggregate: z = (1+eps)*h + sum relu(h[src]+e), bf16 out ----------------
__global__ __launch_bounds__(256) void k_aggregate(const float* __restrict__ h,
    const int* __restrict__ row_off, const int* __restrict__ ssrc,
    const float2* __restrict__ sattr, const float* __restrict__ We_l,
    const float* __restrict__ be_l, const float* __restrict__ epsp, int layer,
    unsigned short* __restrict__ z) {
  int wid = (blockIdx.x * 256 + threadIdx.x) >> 6;
  if (wid >= NN) return;
  int c4 = (threadIdx.x & 63) << 2;
  float4 w0 = *(const float4*)&We_l[c4];
  float4 w1 = *(const float4*)&We_l[EMB + c4];
  float4 bb = *(const float4*)&be_l[c4];
  float4 acc = make_float4(0.f, 0.f, 0.f, 0.f);
  int k0 = row_off[wid], k1 = row_off[wid + 1];
  for (int k = k0; k < k1; ++k) {
    int s = ssrc[k];
    float2 a = sattr[k];
    float4 hv = *(const float4*)&h[(size_t)s * EMB + c4];
    acc.x += fmaxf(hv.x + a.x * w0.x + a.y * w1.x + bb.x, 0.f);
    acc.y += fmaxf(hv.y + a.x * w0.y + a.y * w1.y + bb.y, 0.f);
    acc.z += fmaxf(hv.z + a.x * w0.z + a.y * w1.z + bb.z, 0.f);
    acc.w += fmaxf(hv.w + a.x * w0.w + a.y * w1.w + bb.w, 0.f);
  }
  float e1 = 1.0f + epsp[layer];
  float4 hv = *(const float4*)&h[(size_t)wid * EMB + c4];
  u16x4 o;
  o[0] = f2bf(e1 * hv.x + acc.x);
  o[1] = f2bf(e1 * hv.y + acc.y);
  o[2] = f2bf(e1 * hv.z + acc.z);
  o[3] = f2bf(e1 * hv.w + acc.w);
  *(u16x4*)&z[(size_t)wid * EMB + c4] = o;
}

// ---------------- barrier-free GEMM: C[M x NC] = A[M x K] @ Bt[NC x K]^T ----------------
// B col-panel (CB=NF*16 cols x full K = 64KB) resident in LDS, frag-major lane-linear
// (conflict-free ds_read_b128). A streams global->reg with depth-3 prefetch. No K-loop barrier.
// Block = 4 waves x 32 rows = 128 rows. Grid = (ceil(NN/128), NC/CB).
// MODE 0: +bias -> bf16 Y (via LDS-bounce coalesced store) + col sum/sumsq atomics
// MODE 1: A-path applies relu(a*scale[k]+shift[k]); +bias, relu, f32 out
// MODE 2: same as 1, no output relu
template<int K, int NC, int NF, int MODE>
__global__ __launch_bounds__(256) void k_gemm(
    const unsigned short* __restrict__ A, const unsigned short* __restrict__ Bt,
    const float* __restrict__ bias, const float* __restrict__ scale,
    const float* __restrict__ shift, unsigned short* __restrict__ Ybf,
    float* __restrict__ Hout, float* __restrict__ colsum, float* __restrict__ colsq) {
  constexpr int KT = K / 32;
  constexpr int CB = NF * 16;
  __shared__ __align__(16) unsigned short ldsB[KT * NF * 512];  // 64 KB
  int tid = threadIdx.x, lane = tid & 63, wave = tid >> 6;
  int row0 = blockIdx.x * 128, col0 = blockIdx.y * CB;
  int lr = lane & 15, lg = lane >> 4;

  // ---- stage B once: frag f=kt*NF+n holds lanes' 16B slices contiguously ----
  constexpr int NCH = KT * NF * 64;  // 16B chunks (4096)
#pragma unroll
  for (int it = 0; it < NCH / 256; ++it) {
    int i16 = it * 256 + tid;
    int frag = i16 >> 6, l = i16 & 63;
    int n = frag % NF, kt = frag / NF;
    int col = col0 + n * 16 + (l & 15);
    int k = kt * 32 + (l >> 4) * 8;
    *(u16x8*)&ldsB[i16 * 8] = *(const u16x8*)&Bt[(size_t)col * K + k];
  }
  __syncthreads();

  int row0w = row0 + wave * 32;
  int r0 = row0w + lr;      if (r0 > NN - 1) r0 = NN - 1;
  int r1 = row0w + 16 + lr; if (r1 > NN - 1) r1 = NN - 1;
  const unsigned short* a0p = A + (size_t)r0 * K + lg * 8;
  const unsigned short* a1p = A + (size_t)r1 * K + lg * 8;

  f32x4 acc[2][NF] = {};
  u16x8 ap0[3], ap1[3];
  ap0[0] = *(const u16x8*)(a0p);
  ap1[0] = *(const u16x8*)(a1p);
  ap0[1] = *(const u16x8*)(a0p + 32);
  ap1[1] = *(const u16x8*)(a1p + 32);
  ap0[2] = *(const u16x8*)(a0p + 64);
  ap1[2] = *(const u16x8*)(a1p + 64);

#pragma unroll
  for (int kt = 0; kt < KT; ++kt) {
    U8u am0, am1;
    am0.v = ap0[kt % 3]; am1.v = ap1[kt % 3];
    if (kt + 3 < KT) {
      ap0[kt % 3] = *(const u16x8*)(a0p + (kt + 3) * 32);
      ap1[kt % 3] = *(const u16x8*)(a1p + (kt + 3) * 32);
    }
    bf16x8 af0, af1;
    if constexpr (MODE >= 1) {
      int kb = kt * 32 + lg * 8;
      f32x4 sc0 = *(const f32x4*)&scale[kb], sc1 = *(const f32x4*)&scale[kb + 4];
      f32x4 sh0 = *(const f32x4*)&shift[kb], sh1 = *(const f32x4*)&shift[kb + 4];
      U8u o0, o1;
#pragma unroll
      for (int j = 0; j < 4; ++j) {
        o0.s[j]     = f2bf(fmaxf(bf2f(am0.s[j])     * sc0[j] + sh0[j], 0.f));
        o0.s[4 + j] = f2bf(fmaxf(bf2f(am0.s[4 + j]) * sc1[j] + sh1[j], 0.f));
        o1.s[j]     = f2bf(fmaxf(bf2f(am1.s[j])     * sc0[j] + sh0[j], 0.f));
        o1.s[4 + j] = f2bf(fmaxf(bf2f(am1.s[4 + j]) * sc1[j] + sh1[j], 0.f));
      }
      af0 = o0.b; af1 = o1.b;
    } else {
      af0 = am0.b; af1 = am1.b;
    }
    const unsigned short* bb = &ldsB[(kt * NF) * 512 + lane * 8];
#pragma unroll
    for (int n = 0; n < NF; ++n) {
      U8u bu; bu.v = *(const u16x8*)(bb + n * 512);
      acc[0][n] = __builtin_amdgcn_mfma_f32_16x16x32_bf16(af0, bu.b, acc[0][n], 0, 0, 0);
      acc[1][n] = __builtin_amdgcn_mfma_f32_16x16x32_bf16(af1, bu.b, acc[1][n], 0, 0, 0);
    }
  }

  if constexpr (MODE == 0) {
    // B panel dead; reuse LDS (wave-private 32 x CB f32 = 16KB) for coalesced bf16 store
    __syncthreads();
    float* ldsW = (float*)&ldsB[0] + wave * (32 * CB);
    float cs[NF], cq[NF];
#pragma unroll
    for (int n = 0; n < NF; ++n) { cs[n] = 0.f; cq[n] = 0.f; }
#pragma unroll
    for (int n = 0; n < NF; ++n) {
      float bv = bias[col0 + n * 16 + lr];
#pragma unroll
      for (int m = 0; m < 2; ++m)
#pragma unroll
        for (int j = 0; j < 4; ++j) {
          float v = acc[m][n][j] + bv;
          int gr = row0w + m * 16 + lg * 4 + j;
          if (gr < NN) { cs[n] += v; cq[n] += v * v; }
          ldsW[(m * 16 + lg * 4 + j) * CB + n * 16 + lr] = v;
        }
    }
#pragma unroll
    for (int n = 0; n < NF; ++n) {
      cs[n] += __shfl_xor(cs[n], 16, 64); cs[n] += __shfl_xor(cs[n], 32, 64);
      cq[n] += __shfl_xor(cq[n], 16, 64); cq[n] += __shfl_xor(cq[n], 32, 64);
    }
    if (lg == 0) {
#pragma unroll
      for (int n = 0; n < NF; ++n) {
        atomicAdd(&colsum[col0 + n * 16 + lr], cs[n]);
        atomicAdd(&colsq[col0 + n * 16 + lr], cq[n]);
      }
    }
    asm volatile("s_waitcnt lgkmcnt(0)" ::: "memory");
#pragma unroll
    for (int it = 0; it < (32 * CB) / 512; ++it) {
      int e = it * 512 + lane * 8;
      int row = e / CB, colr = e % CB;
      int gr = row0w + row;
      if (gr < NN) {
        f32x4 v0 = *(const f32x4*)&ldsW[e];
        f32x4 v1 = *(const f32x4*)&ldsW[e + 4];
        U8u o;
#pragma unroll
        for (int j = 0; j < 4; ++j) { o.s[j] = f2bf(v0[j]); o.s[4 + j] = f2bf(v1[j]); }
        *(u16x8*)&Ybf[(size_t)gr * NC + col0 + colr] = o.v;
      }
    }
  } else {
    // f32 stores: 16 lanes x 4B = full 64B lines, no bounce needed
#pragma unroll
    for (int n = 0; n < NF; ++n) {
      int gc = col0 + n * 16 + lr;
      float bv = bias[gc];
#pragma unroll
      for (int m = 0; m < 2; ++m) {
        int grb = row0w + m * 16 + lg * 4;
#pragma unroll
        for (int j = 0; j < 4; ++j) {
          int gr = grb + j;
          if (gr < NN) {
            float v = acc[m][n][j] + bv;
            if constexpr (MODE == 1) v = fmaxf(v, 0.f);
            Hout[(size_t)gr * NC + gc] = v;
          }
        }
      }
    }
  }
}

// ---------------- BN finalize ----------------
__global__ void k_bnfin(const float* __restrict__ colsum, const float* __restrict__ colsq,
    const float* __restrict__ gamma, const float* __restrict__ beta,
    float* __restrict__ scale, float* __restrict__ shift) {
  int c = threadIdx.x;
  float inv_n = 1.0f / (float)NN;
  float mu = colsum[c] * inv_n;
  float var = colsq[c] * inv_n - mu * mu;
  float rstd = rsqrtf(var + 1e-5f);
  float sc = rstd * gamma[c];
  scale[c] = sc;
  shift[c] = beta[c] - mu * sc;
}

extern "C" void kernel_launch(void* const* d_in, const int* in_sizes, int n_in,
                              void* d_out, int out_size, void* d_ws, size_t ws_size,
                              hipStream_t stream) {
  (void)in_sizes; (void)n_in; (void)out_size; (void)ws_size;
  const int* node_ids    = (const int*)d_in[0];
  const int* node_depth  = (const int*)d_in[1];
  const int* edge_index  = (const int*)d_in[2];
  const float* edge_attr = (const float*)d_in[3];
  const float* temb      = (const float*)d_in[4];
  const float* demb      = (const float*)d_in[5];
  const float* We        = (const float*)d_in[6];
  const float* be        = (const float*)d_in[7];
  const float* W1        = (const float*)d_in[8];
  const float* b1        = (const float*)d_in[9];
  const float* gamma_    = (const float*)d_in[10];
  const float* beta_     = (const float*)d_in[11];
  const float* W2        = (const float*)d_in[12];
  const float* b2        = (const float*)d_in[13];
  const float* epsp      = (const float*)d_in[14];
  float* h = (float*)d_out;

  char* ws = (char*)d_ws;
  size_t off = 0;
  auto alloc = [&](size_t bytes) -> void* {
    void* p = ws + off;
    off = (off + bytes + 255) & ~(size_t)255;
    return p;
  };
  unsigned short* z   = (unsigned short*)alloc(2ull * NN * EMB);        // 25.6 MB
  unsigned short* y   = (unsigned short*)alloc(2ull * NN * HID);        // 51.2 MB
  unsigned short* W1t = (unsigned short*)alloc(2ull * NL * EMB * HID);  // 1.3 MB
  unsigned short* W2t = (unsigned short*)alloc(2ull * NL * HID * EMB);  // 1.3 MB
  int* deg      = (int*)alloc(sizeof(int) * NN);
  int* row_off  = (int*)alloc(sizeof(int) * (NN + 1));
  int* cursor   = (int*)alloc(sizeof(int) * NN);
  int* ssrc     = (int*)alloc(sizeof(int) * NE);
  float2* sattr = (float2*)alloc(sizeof(float2) * NE);
  int* bsums    = (int*)alloc(sizeof(int) * 256);
  float* colsum = (float*)alloc(sizeof(float) * HID * 2);
  float* colsq  = colsum + HID;
  float* scale  = (float*)alloc(sizeof(float) * HID);
  float* shift  = (float*)alloc(sizeof(float) * HID);

  const int* e_src = edge_index;
  const int* e_dst = edge_index + NE;

  k_init_h<<<(NN * 64) / 256, 256, 0, stream>>>(node_ids, node_depth, temb, demb, h);
  hipMemsetAsync(deg, 0, sizeof(int) * NN, stream);
  k_count<<<(NE + 255) / 256, 256, 0, stream>>>(e_dst, deg);
  k_scan1<<<49, 256, 0, stream>>>(deg, row_off, bsums);
  k_scan2<<<1, 256, 0, stream>>>(bsums, 49);
  k_scan3<<<49, 256, 0, stream>>>(row_off, bsums);
  k_copy<<<(NN + 255) / 256, 256, 0, stream>>>(row_off, cursor);
  k_fill<<<(NE + 255) / 256, 256, 0, stream>>>(e_src, e_dst, edge_attr, cursor, ssrc, sattr);
  // weights: W1 [L][EMB][HID] -> W1t [L][HID][EMB]; W2 [L][HID][EMB] -> W2t [L][EMB][HID]
  k_convW<<<dim3(HID / 32, EMB / 32, NL), 256, 0, stream>>>(W1, W1t, EMB, HID);
  k_convW<<<dim3(EMB / 32, HID / 32, NL), 256, 0, stream>>>(W2, W2t, HID, EMB);

  const int MB = (NN + 127) / 128;  // 391
  for (int l = 0; l < NL; ++l) {
    k_aggregate<<<(NN * 64) / 256, 256, 0, stream>>>(
        h, row_off, ssrc, sattr, We + (size_t)l * 2 * EMB, be + (size_t)l * EMB, epsp, l, z);
    hipMemsetAsync(colsum, 0, sizeof(float) * HID * 2, stream);
    // GEMM1: A=z [NN][256], Bt=W1t [512][256], out y bf16 + col stats. CB=128.
    k_gemm<EMB, HID, 8, 0><<<dim3(MB, HID / 128), 256, 0, stream>>>(
        z, W1t + (size_t)l * EMB * HID, b1 + (size_t)l * HID,
        nullptr, nullptr, y, nullptr, colsum, colsq);
    k_bnfin<<<1, HID, 0, stream>>>(colsum, colsq, gamma_ + (size_t)l * HID,
                                   beta_ + (size_t)l * HID, scale, shift);
    // GEMM2: A=y [NN][512] (BN+ReLU fused), Bt=W2t [256][512], out h f32. CB=64.
    if (l < NL - 1)
      k_gemm<HID, EMB, 4, 1><<<dim3(MB, EMB / 64), 256, 0, stream>>>(
          y, W2t + (size_t)l * HID * EMB, b2 + (size_t)l * EMB,
          scale, shift, nullptr, h, nullptr, nullptr);
    else
      k_gemm<HID, EMB, 4, 2><<<dim3(MB, EMB / 64), 256, 0, stream>>>(
          y, W2t + (size_t)l * HID * EMB, b2 + (size_t)l * EMB,
          scale, shift, nullptr, h, nullptr, nullptr);
  }
}

// Round 9
// 1249.946 us; speedup vs baseline: 1.1225x; 1.1225x over previous
//
#include <hip/hip_runtime.h>

#define NN 50000
#define NE 300000
#define EMB 256
#define HID 512
#define NL 5

typedef __attribute__((ext_vector_type(8))) short bf16x8;
typedef __attribute__((ext_vector_type(4))) float f32x4;
typedef __attribute__((ext_vector_type(8))) unsigned short u16x8;
typedef __attribute__((ext_vector_type(4))) unsigned short u16x4;

union U8u { u16x8 v; bf16x8 b; unsigned short s[8]; };

__device__ __forceinline__ float bf2f(unsigned short u) {
  union { unsigned int i; float f; } c; c.i = ((unsigned int)u) << 16; return c.f;
}
__device__ __forceinline__ unsigned short f2bf(float f) {
  union { float f; unsigned int i; } c; c.f = f;
  unsigned int r = c.i + 0x7FFF + ((c.i >> 16) & 1);
  return (unsigned short)(r >> 16);
}

// ---------------- node encoder ----------------
__global__ __launch_bounds__(256) void k_init_h(const int* __restrict__ ids,
    const int* __restrict__ depth, const float* __restrict__ temb,
    const float* __restrict__ demb, float* __restrict__ h) {
  int gid = blockIdx.x * 256 + threadIdx.x;
  int row = gid >> 6;
  if (row >= NN) return;
  int c4 = (gid & 63) << 2;
  int id = ids[row];
  int d = depth[row]; d = d < 0 ? 0 : (d > 20 ? 20 : d);
  float4 a = *(const float4*)&temb[id * EMB + c4];
  float4 b = *(const float4*)&demb[d * EMB + c4];
  *(float4*)&h[row * EMB + c4] = make_float4(a.x + b.x, a.y + b.y, a.z + b.z, a.w + b.w);
}

// ---------------- CSR build ----------------
__global__ __launch_bounds__(256) void k_count(const int* __restrict__ dst, int* __restrict__ deg) {
  int e = blockIdx.x * 256 + threadIdx.x;
  if (e < NE) atomicAdd(&deg[dst[e]], 1);
}
__global__ __launch_bounds__(256) void k_scan1(const int* __restrict__ deg,
    int* __restrict__ row_off, int* __restrict__ bsums) {
  __shared__ int lds[256];
  int b = blockIdx.x, t = threadIdx.x;
  int base = b * 1024;
  int v[4]; int s = 0;
  for (int i = 0; i < 4; ++i) {
    int idx = base + t * 4 + i;
    v[i] = (idx < NN) ? deg[idx] : 0;
    s += v[i];
  }
  lds[t] = s; __syncthreads();
  for (int off = 1; off < 256; off <<= 1) {
    int x = (t >= off) ? lds[t - off] : 0; __syncthreads();
    lds[t] += x; __syncthreads();
  }
  int run = (t > 0) ? lds[t - 1] : 0;
  if (t == 255) bsums[b] = lds[255];
  for (int i = 0; i < 4; ++i) {
    int idx = base + t * 4 + i;
    if (idx < NN) row_off[idx] = run;
    run += v[i];
  }
}
__global__ __launch_bounds__(256) void k_scan2(int* __restrict__ bsums, int nb) {
  __shared__ int lds[256];
  int t = threadIdx.x;
  int v = (t < nb) ? bsums[t] : 0;
  lds[t] = v; __syncthreads();
  for (int off = 1; off < 256; off <<= 1) {
    int x = (t >= off) ? lds[t - off] : 0; __syncthreads();
    lds[t] += x; __syncthreads();
  }
  if (t < nb) bsums[t] = (t > 0) ? lds[t - 1] : 0;
}
__global__ __launch_bounds__(256) void k_scan3(int* __restrict__ row_off, const int* __restrict__ bsums) {
  int b = blockIdx.x, t = threadIdx.x;
  int base = b * 1024;
  int add = bsums[b];
  for (int i = 0; i < 4; ++i) {
    int idx = base + t * 4 + i;
    if (idx < NN) row_off[idx] += add;
  }
  if (b == 0 && t == 0) row_off[NN] = NE;
}
__global__ __launch_bounds__(256) void k_copy(const int* __restrict__ a, int* __restrict__ b) {
  int i = blockIdx.x * 256 + threadIdx.x;
  if (i < NN) b[i] = a[i];
}
__global__ __launch_bounds__(256) void k_fill(const int* __restrict__ src, const int* __restrict__ dst,
    const float* __restrict__ attr, int* __restrict__ cursor,
    int* __restrict__ ssrc, float2* __restrict__ sattr) {
  int e = blockIdx.x * 256 + threadIdx.x;
  if (e >= NE) return;
  int d = dst[e];
  int p = atomicAdd(&cursor[d], 1);
  ssrc[p] = src[e];
  sattr[p] = make_float2(attr[2 * e], attr[2 * e + 1]);
}

// ---------------- weight transpose + bf16 convert: W[R][C] -> Wt[C][R] ----------------
__global__ __launch_bounds__(256) void k_convW(const float* __restrict__ W,
    unsigned short* __restrict__ Wt, int R, int C) {
  __shared__ float t[32][33];
  int l = blockIdx.z;
  const float* Wl = W + (size_t)l * R * C;
  unsigned short* Wtl = Wt + (size_t)l * R * C;
  int c0 = blockIdx.x * 32, r0 = blockIdx.y * 32;
  int tx = threadIdx.x & 31, ty = threadIdx.x >> 5;  // ty 0..7
  for (int i = 0; i < 32; i += 8)
    t[ty + i][tx] = Wl[(size_t)(r0 + ty + i) * C + c0 + tx];
  __syncthreads();
  for (int i = 0; i < 32; i += 8)
    Wtl[(size_t)(c0 + ty + i) * R + r0 + tx] = f2bf(t[tx][ty + i]);
}

// ---------------- per-layer aggregate: z = (1+eps)*h + sum relu(h[src]+e), bf16 out ----------------
__global__ __launch_bounds__(256) void k_aggregate(const float* __restrict__ h,
    const int* __restrict__ row_off, const int* __restrict__ ssrc,
    const float2* __restrict__ sattr, const float* __restrict__ We_l,
    const float* __restrict__ be_l, const float* __restrict__ epsp, int layer,
    unsigned short* __restrict__ z) {
  int wid = (blockIdx.x * 256 + threadIdx.x) >> 6;
  if (wid >= NN) return;
  int c4 = (threadIdx.x & 63) << 2;
  float4 w0 = *(const float4*)&We_l[c4];
  float4 w1 = *(const float4*)&We_l[EMB + c4];
  float4 bb = *(const float4*)&be_l[c4];
  float4 acc = make_float4(0.f, 0.f, 0.f, 0.f);
  int k0 = row_off[wid], k1 = row_off[wid + 1];
  for (int k = k0; k < k1; ++k) {
    int s = ssrc[k];
    float2 a = sattr[k];
    float4 hv = *(const float4*)&h[(size_t)s * EMB + c4];
    acc.x += fmaxf(hv.x + a.x * w0.x + a.y * w1.x + bb.x, 0.f);
    acc.y += fmaxf(hv.y + a.x * w0.y + a.y * w1.y + bb.y, 0.f);
    acc.z += fmaxf(hv.z + a.x * w0.z + a.y * w1.z + bb.z, 0.f);
    acc.w += fmaxf(hv.w + a.x * w0.w + a.y * w1.w + bb.w, 0.f);
  }
  float e1 = 1.0f + epsp[layer];
  float4 hv = *(const float4*)&h[(size_t)wid * EMB + c4];
  u16x4 o;
  o[0] = f2bf(e1 * hv.x + acc.x);
  o[1] = f2bf(e1 * hv.y + acc.y);
  o[2] = f2bf(e1 * hv.z + acc.z);
  o[3] = f2bf(e1 * hv.w + acc.w);
  *(u16x4*)&z[(size_t)wid * EMB + c4] = o;
}

// ---------------- MFMA GEMM (v1 structure + T14 split + swapped-operand epilogue) ------
// C[M x NC] = A[M x K](bf16) @ Bt[NC x K](bf16)^T. 128x128 tile, BK=32, 2-buf LDS (32KB).
// Staging: global->reg issued BEFORE compute, transform+ds_write AFTER (latency hidden).
// MFMA called as mfma(B_frag, A_frag, acc) so lane holds row=wr+m*16+(lane&15),
// cols=wc+n*16+(lane>>4)*4+{0..3} -> 8B/16B contiguous per-lane stores (coalesced).
// MODE 0: +bias -> bf16 Y + column sum/sumsq atomics
// MODE 1: A-staging applies relu(a*scale[k]+shift[k]); +bias, relu, f32 out
// MODE 2: same as 1, no output relu
template<int K, int NC, int MODE>
__global__ __launch_bounds__(256) void k_gemm(
    const unsigned short* __restrict__ A, const unsigned short* __restrict__ Bt,
    const float* __restrict__ bias, const float* __restrict__ scale,
    const float* __restrict__ shift, unsigned short* __restrict__ Ybf,
    float* __restrict__ Hout, float* __restrict__ colsum, float* __restrict__ colsq) {
  constexpr int KT = K / 32;
  __shared__ __align__(16) unsigned short lA[2][128 * 32];
  __shared__ __align__(16) unsigned short lB[2][128 * 32];
  const int tid = threadIdx.x;
  const int lane = tid & 63, wave = tid >> 6;
  const int lr = lane & 15, lg = lane >> 4;
  const int wr = (wave >> 1) * 64, wc = (wave & 1) * 64;
  const int col0 = blockIdx.x * 128, row0 = blockIdx.y * 128;

  // per-thread staging: thread t covers tile-row t>>1, k-half (t&1)*16 (32B = 2 x u16x8)
  const int rA = tid >> 1;
  const int hA = (tid & 1) * 16;
  int grs = row0 + rA; if (grs > NN - 1) grs = NN - 1;  // clamp (dupes excluded in epilogue)
  const unsigned short* aSrc = A + (size_t)grs * K + hA;
  const unsigned short* bSrc = Bt + (size_t)(col0 + rA) * K + hA;
  unsigned short* aDst = &lA[0][0] + rA * 32 + hA;
  unsigned short* bDst = &lB[0][0] + rA * 32 + hA;

  f32x4 acc[4][4] = {};
  u16x8 ra0, ra1, rb0, rb1;
  f32x4 sc[4], sh[4];

  auto tload = [&](int kt) {
    ra0 = *(const u16x8*)(aSrc + kt * 32);
    ra1 = *(const u16x8*)(aSrc + kt * 32 + 8);
    rb0 = *(const u16x8*)(bSrc + kt * 32);
    rb1 = *(const u16x8*)(bSrc + kt * 32 + 8);
    if constexpr (MODE >= 1) {
      int kb = kt * 32 + hA;
#pragma unroll
      for (int q = 0; q < 4; ++q) {
        sc[q] = *(const f32x4*)&scale[kb + q * 4];
        sh[q] = *(const f32x4*)&shift[kb + q * 4];
      }
    }
  };
  auto twrite = [&](int buf) {
    u16x8 wa0 = ra0, wa1 = ra1;
    if constexpr (MODE >= 1) {
      U8u a0, a1, o0, o1;
      a0.v = ra0; a1.v = ra1;
#pragma unroll
      for (int j = 0; j < 4; ++j) {
        o0.s[j]     = f2bf(fmaxf(bf2f(a0.s[j])     * sc[0][j] + sh[0][j], 0.f));
        o0.s[4 + j] = f2bf(fmaxf(bf2f(a0.s[4 + j]) * sc[1][j] + sh[1][j], 0.f));
        o1.s[j]     = f2bf(fmaxf(bf2f(a1.s[j])     * sc[2][j] + sh[2][j], 0.f));
        o1.s[4 + j] = f2bf(fmaxf(bf2f(a1.s[4 + j]) * sc[3][j] + sh[3][j], 0.f));
      }
      wa0 = o0.v; wa1 = o1.v;
    }
    *(u16x8*)(aDst + buf * 4096) = wa0;
    *(u16x8*)(aDst + buf * 4096 + 8) = wa1;
    *(u16x8*)(bDst + buf * 4096) = rb0;
    *(u16x8*)(bDst + buf * 4096 + 8) = rb1;
  };

  tload(0); twrite(0);
  __syncthreads();
  int buf = 0;
  for (int kt = 0; kt < KT; ++kt) {
    if (kt + 1 < KT) tload(kt + 1);     // issue loads early (latency hides under MFMA)
    bf16x8 af[4], bfr[4];
#pragma unroll
    for (int m = 0; m < 4; ++m)
      af[m] = *(const bf16x8*)&lA[buf][(wr + m * 16 + lr) * 32 + lg * 8];
#pragma unroll
    for (int n = 0; n < 4; ++n)
      bfr[n] = *(const bf16x8*)&lB[buf][(wc + n * 16 + lr) * 32 + lg * 8];
#pragma unroll
    for (int m = 0; m < 4; ++m)
#pragma unroll
      for (int n = 0; n < 4; ++n)
        acc[m][n] = __builtin_amdgcn_mfma_f32_16x16x32_bf16(bfr[n], af[m], acc[m][n], 0, 0, 0);
    if (kt + 1 < KT) twrite(buf ^ 1);   // write late (after compute)
    __syncthreads();
    buf ^= 1;
  }

  if constexpr (MODE == 0) {
    f32x4 csum[4] = {}, csq[4] = {};
#pragma unroll
    for (int n = 0; n < 4; ++n) {
      const int gcB = col0 + wc + n * 16 + lg * 4;
      f32x4 bv = *(const f32x4*)&bias[gcB];
#pragma unroll
      for (int m = 0; m < 4; ++m) {
        int gr = row0 + wr + m * 16 + lr;
        if (gr < NN) {
          f32x4 v = acc[m][n] + bv;
          u16x4 o;
#pragma unroll
          for (int j = 0; j < 4; ++j) o[j] = f2bf(v[j]);
          *(u16x4*)&Ybf[(size_t)gr * NC + gcB] = o;
          csum[n] += v;
          csq[n] += v * v;
        }
      }
    }
#pragma unroll
    for (int n = 0; n < 4; ++n)
#pragma unroll
      for (int j = 0; j < 4; ++j) {
        float s = csum[n][j], q = csq[n][j];
        s += __shfl_xor(s, 1, 64); q += __shfl_xor(q, 1, 64);
        s += __shfl_xor(s, 2, 64); q += __shfl_xor(q, 2, 64);
        s += __shfl_xor(s, 4, 64); q += __shfl_xor(q, 4, 64);
        s += __shfl_xor(s, 8, 64); q += __shfl_xor(q, 8, 64);
        if (lr == 0) {
          atomicAdd(&colsum[col0 + wc + n * 16 + lg * 4 + j], s);
          atomicAdd(&colsq[col0 + wc + n * 16 + lg * 4 + j], q);
        }
      }
  } else {
#pragma unroll
    for (int n = 0; n < 4; ++n) {
      const int gcB = col0 + wc + n * 16 + lg * 4;
      f32x4 bv = *(const f32x4*)&bias[gcB];
#pragma unroll
      for (int m = 0; m < 4; ++m) {
        int gr = row0 + wr + m * 16 + lr;
        if (gr < NN) {
          f32x4 v = acc[m][n] + bv;
          if constexpr (MODE == 1) {
#pragma unroll
            for (int j = 0; j < 4; ++j) v[j] = fmaxf(v[j], 0.f);
          }
          *(f32x4*)&Hout[(size_t)gr * NC + gcB] = v;
        }
      }
    }
  }
}

// ---------------- BN finalize ----------------
__global__ void k_bnfin(const float* __restrict__ colsum, const float* __restrict__ colsq,
    const float* __restrict__ gamma, const float* __restrict__ beta,
    float* __restrict__ scale, float* __restrict__ shift) {
  int c = threadIdx.x;
  float inv_n = 1.0f / (float)NN;
  float mu = colsum[c] * inv_n;
  float var = colsq[c] * inv_n - mu * mu;
  float rstd = rsqrtf(var + 1e-5f);
  float sc = rstd * gamma[c];
  scale[c] = sc;
  shift[c] = beta[c] - mu * sc;
}

extern "C" void kernel_launch(void* const* d_in, const int* in_sizes, int n_in,
                              void* d_out, int out_size, void* d_ws, size_t ws_size,
                              hipStream_t stream) {
  (void)in_sizes; (void)n_in; (void)out_size; (void)ws_size;
  const int* node_ids    = (const int*)d_in[0];
  const int* node_depth  = (const int*)d_in[1];
  const int* edge_index  = (const int*)d_in[2];
  const float* edge_attr = (const float*)d_in[3];
  const float* temb      = (const float*)d_in[4];
  const float* demb      = (const float*)d_in[5];
  const float* We        = (const float*)d_in[6];
  const float* be        = (const float*)d_in[7];
  const float* W1        = (const float*)d_in[8];
  const float* b1        = (const float*)d_in[9];
  const float* gamma_    = (const float*)d_in[10];
  const float* beta_     = (const float*)d_in[11];
  const float* W2        = (const float*)d_in[12];
  const float* b2        = (const float*)d_in[13];
  const float* epsp      = (const float*)d_in[14];
  float* h = (float*)d_out;

  char* ws = (char*)d_ws;
  size_t off = 0;
  auto alloc = [&](size_t bytes) -> void* {
    void* p = ws + off;
    off = (off + bytes + 255) & ~(size_t)255;
    return p;
  };
  unsigned short* z   = (unsigned short*)alloc(2ull * NN * EMB);        // 25.6 MB
  unsigned short* y   = (unsigned short*)alloc(2ull * NN * HID);        // 51.2 MB
  unsigned short* W1t = (unsigned short*)alloc(2ull * NL * EMB * HID);  // 1.3 MB
  unsigned short* W2t = (unsigned short*)alloc(2ull * NL * HID * EMB);  // 1.3 MB
  int* deg      = (int*)alloc(sizeof(int) * NN);
  int* row_off  = (int*)alloc(sizeof(int) * (NN + 1));
  int* cursor   = (int*)alloc(sizeof(int) * NN);
  int* ssrc     = (int*)alloc(sizeof(int) * NE);
  float2* sattr = (float2*)alloc(sizeof(float2) * NE);
  int* bsums    = (int*)alloc(sizeof(int) * 256);
  float* colsum = (float*)alloc(sizeof(float) * HID * 2);
  float* colsq  = colsum + HID;
  float* scale  = (float*)alloc(sizeof(float) * HID);
  float* shift  = (float*)alloc(sizeof(float) * HID);

  const int* e_src = edge_index;
  const int* e_dst = edge_index + NE;

  k_init_h<<<(NN * 64) / 256, 256, 0, stream>>>(node_ids, node_depth, temb, demb, h);
  hipMemsetAsync(deg, 0, sizeof(int) * NN, stream);
  k_count<<<(NE + 255) / 256, 256, 0, stream>>>(e_dst, deg);
  k_scan1<<<49, 256, 0, stream>>>(deg, row_off, bsums);
  k_scan2<<<1, 256, 0, stream>>>(bsums, 49);
  k_scan3<<<49, 256, 0, stream>>>(row_off, bsums);
  k_copy<<<(NN + 255) / 256, 256, 0, stream>>>(row_off, cursor);
  k_fill<<<(NE + 255) / 256, 256, 0, stream>>>(e_src, e_dst, edge_attr, cursor, ssrc, sattr);
  // weights: W1 [L][EMB][HID] -> W1t [L][HID][EMB]; W2 [L][HID][EMB] -> W2t [L][EMB][HID]
  k_convW<<<dim3(HID / 32, EMB / 32, NL), 256, 0, stream>>>(W1, W1t, EMB, HID);
  k_convW<<<dim3(EMB / 32, HID / 32, NL), 256, 0, stream>>>(W2, W2t, HID, EMB);

  const int MB = (NN + 127) / 128;  // 391
  for (int l = 0; l < NL; ++l) {
    k_aggregate<<<(NN * 64) / 256, 256, 0, stream>>>(
        h, row_off, ssrc, sattr, We + (size_t)l * 2 * EMB, be + (size_t)l * EMB, epsp, l, z);
    hipMemsetAsync(colsum, 0, sizeof(float) * HID * 2, stream);
    // GEMM1: A=z [NN][256], Bt=W1t [512][256]; grid.x = col-blocks (adjacent dispatch
    // shares the A row-panel -> L2 reuse), grid.y = row-blocks.
    k_gemm<EMB, HID, 0><<<dim3(HID / 128, MB), 256, 0, stream>>>(
        z, W1t + (size_t)l * EMB * HID, b1 + (size_t)l * HID,
        nullptr, nullptr, y, nullptr, colsum, colsq);
    k_bnfin<<<1, HID, 0, stream>>>(colsum, colsq, gamma_ + (size_t)l * HID,
                                   beta_ + (size_t)l * HID, scale, shift);
    // GEMM2: A=y [NN][512] (BN+ReLU fused in staging), Bt=W2t [256][512], f32 out.
    if (l < NL - 1)
      k_gemm<HID, EMB, 1><<<dim3(EMB / 128, MB), 256, 0, stream>>>(
          y, W2t + (size_t)l * HID * EMB, b2 + (size_t)l * EMB,
          scale, shift, nullptr, h, nullptr, nullptr);
    else
      k_gemm<HID, EMB, 2><<<dim3(EMB / 128, MB), 256, 0, stream>>>(
          y, W2t + (size_t)l * HID * EMB, b2 + (size_t)l * EMB,
          scale, shift, nullptr, h, nullptr, nullptr);
  }
}

// Round 10
// 1221.547 us; speedup vs baseline: 1.1486x; 1.0232x over previous
//
#include <hip/hip_runtime.h>

#define NN 50000
#define NE 300000
#define EMB 256
#define HID 512
#define NL 5

typedef __attribute__((ext_vector_type(8))) short bf16x8;
typedef __attribute__((ext_vector_type(4))) float f32x4;
typedef __attribute__((ext_vector_type(8))) unsigned short u16x8;
typedef __attribute__((ext_vector_type(4))) unsigned short u16x4;

union U8u { u16x8 v; bf16x8 b; unsigned short s[8]; };

__device__ __forceinline__ float bf2f(unsigned short u) {
  union { unsigned int i; float f; } c; c.i = ((unsigned int)u) << 16; return c.f;
}
__device__ __forceinline__ unsigned short f2bf(float f) {
  union { float f; unsigned int i; } c; c.f = f;
  unsigned int r = c.i + 0x7FFF + ((c.i >> 16) & 1);
  return (unsigned short)(r >> 16);
}
// async global->LDS, 16B per lane; LDS dest = wave-uniform base + lane*16
__device__ __forceinline__ void gload_lds16(const void* g, void* l) {
  __builtin_amdgcn_global_load_lds(
      (const __attribute__((address_space(1))) void*)g,
      (__attribute__((address_space(3))) void*)l, 16, 0, 0);
}

// ---------------- node encoder ----------------
__global__ __launch_bounds__(256) void k_init_h(const int* __restrict__ ids,
    const int* __restrict__ depth, const float* __restrict__ temb,
    const float* __restrict__ demb, float* __restrict__ h) {
  int gid = blockIdx.x * 256 + threadIdx.x;
  int row = gid >> 6;
  if (row >= NN) return;
  int c4 = (gid & 63) << 2;
  int id = ids[row];
  int d = depth[row]; d = d < 0 ? 0 : (d > 20 ? 20 : d);
  float4 a = *(const float4*)&temb[id * EMB + c4];
  float4 b = *(const float4*)&demb[d * EMB + c4];
  *(float4*)&h[row * EMB + c4] = make_float4(a.x + b.x, a.y + b.y, a.z + b.z, a.w + b.w);
}

// ---------------- CSR build ----------------
__global__ __launch_bounds__(256) void k_count(const int* __restrict__ dst, int* __restrict__ deg) {
  int e = blockIdx.x * 256 + threadIdx.x;
  if (e < NE) atomicAdd(&deg[dst[e]], 1);
}
__global__ __launch_bounds__(256) void k_scan1(const int* __restrict__ deg,
    int* __restrict__ row_off, int* __restrict__ bsums) {
  __shared__ int lds[256];
  int b = blockIdx.x, t = threadIdx.x;
  int base = b * 1024;
  int v[4]; int s = 0;
  for (int i = 0; i < 4; ++i) {
    int idx = base + t * 4 + i;
    v[i] = (idx < NN) ? deg[idx] : 0;
    s += v[i];
  }
  lds[t] = s; __syncthreads();
  for (int off = 1; off < 256; off <<= 1) {
    int x = (t >= off) ? lds[t - off] : 0; __syncthreads();
    lds[t] += x; __syncthreads();
  }
  int run = (t > 0) ? lds[t - 1] : 0;
  if (t == 255) bsums[b] = lds[255];
  for (int i = 0; i < 4; ++i) {
    int idx = base + t * 4 + i;
    if (idx < NN) row_off[idx] = run;
    run += v[i];
  }
}
__global__ __launch_bounds__(256) void k_scan2(int* __restrict__ bsums, int nb) {
  __shared__ int lds[256];
  int t = threadIdx.x;
  int v = (t < nb) ? bsums[t] : 0;
  lds[t] = v; __syncthreads();
  for (int off = 1; off < 256; off <<= 1) {
    int x = (t >= off) ? lds[t - off] : 0; __syncthreads();
    lds[t] += x; __syncthreads();
  }
  if (t < nb) bsums[t] = (t > 0) ? lds[t - 1] : 0;
}
__global__ __launch_bounds__(256) void k_scan3(int* __restrict__ row_off, const int* __restrict__ bsums) {
  int b = blockIdx.x, t = threadIdx.x;
  int base = b * 1024;
  int add = bsums[b];
  for (int i = 0; i < 4; ++i) {
    int idx = base + t * 4 + i;
    if (idx < NN) row_off[idx] += add;
  }
  if (b == 0 && t == 0) row_off[NN] = NE;
}
__global__ __launch_bounds__(256) void k_copy(const int* __restrict__ a, int* __restrict__ b) {
  int i = blockIdx.x * 256 + threadIdx.x;
  if (i < NN) b[i] = a[i];
}
__global__ __launch_bounds__(256) void k_fill(const int* __restrict__ src, const int* __restrict__ dst,
    const float* __restrict__ attr, int* __restrict__ cursor,
    int* __restrict__ ssrc, float2* __restrict__ sattr) {
  int e = blockIdx.x * 256 + threadIdx.x;
  if (e >= NE) return;
  int d = dst[e];
  int p = atomicAdd(&cursor[d], 1);
  ssrc[p] = src[e];
  sattr[p] = make_float2(attr[2 * e], attr[2 * e + 1]);
}

// ---------------- weight transpose + bf16 convert: W[R][C] -> Wt[C][R] ----------------
__global__ __launch_bounds__(256) void k_convW(const float* __restrict__ W,
    unsigned short* __restrict__ Wt, int R, int C) {
  __shared__ float t[32][33];
  int l = blockIdx.z;
  const float* Wl = W + (size_t)l * R * C;
  unsigned short* Wtl = Wt + (size_t)l * R * C;
  int c0 = blockIdx.x * 32, r0 = blockIdx.y * 32;
  int tx = threadIdx.x & 31, ty = threadIdx.x >> 5;  // ty 0..7
  for (int i = 0; i < 32; i += 8)
    t[ty + i][tx] = Wl[(size_t)(r0 + ty + i) * C + c0 + tx];
  __syncthreads();
  for (int i = 0; i < 32; i += 8)
    Wtl[(size_t)(c0 + ty + i) * R + r0 + tx] = f2bf(t[tx][ty + i]);
}

// ---------------- per-layer aggregate: z = (1+eps)*h + sum relu(h[src]+e), bf16 out ----------------
__global__ __launch_bounds__(256) void k_aggregate(const float* __restrict__ h,
    const int* __restrict__ row_off, const int* __restrict__ ssrc,
    const float2* __restrict__ sattr, const float* __restrict__ We_l,
    const float* __restrict__ be_l, const float* __restrict__ epsp, int layer,
    unsigned short* __restrict__ z) {
  int wid = (blockIdx.x * 256 + threadIdx.x) >> 6;
  if (wid >= NN) return;
  int c4 = (threadIdx.x & 63) << 2;
  float4 w0 = *(const float4*)&We_l[c4];
  float4 w1 = *(const float4*)&We_l[EMB + c4];
  float4 bb = *(const float4*)&be_l[c4];
  float4 acc = make_float4(0.f, 0.f, 0.f, 0.f);
  int k0 = row_off[wid], k1 = row_off[wid + 1];
  for (int k = k0; k < k1; ++k) {
    int s = ssrc[k];
    float2 a = sattr[k];
    float4 hv = *(const float4*)&h[(size_t)s * EMB + c4];
    acc.x += fmaxf(hv.x + a.x * w0.x + a.y * w1.x + bb.x, 0.f);
    acc.y += fmaxf(hv.y + a.x * w0.y + a.y * w1.y + bb.y, 0.f);
    acc.z += fmaxf(hv.z + a.x * w0.z + a.y * w1.z + bb.z, 0.f);
    acc.w += fmaxf(hv.w + a.x * w0.w + a.y * w1.w + bb.w, 0.f);
  }
  float e1 = 1.0f + epsp[layer];
  float4 hv = *(const float4*)&h[(size_t)wid * EMB + c4];
  u16x4 o;
  o[0] = f2bf(e1 * hv.x + acc.x);
  o[1] = f2bf(e1 * hv.y + acc.y);
  o[2] = f2bf(e1 * hv.z + acc.z);
  o[3] = f2bf(e1 * hv.w + acc.w);
  *(u16x4*)&z[(size_t)wid * EMB + c4] = o;
}

// ---------------- MFMA GEMM (m97-style: global_load_lds staging) ----------------
// C[M x NC] = A[M x K](bf16) @ Bt[NC x K](bf16)^T. 128x128 tile, BK=32, double-buffered
// 32KB LDS, staged entirely via async global_load_lds (16B/lane, lane-linear layout).
// 1-D grid decoded XCD-aware: b%8 = XCD, col fastest within XCD -> the NCB col-blocks
// sharing one A row-panel run on the same XCD's L2.
// Swapped-operand MFMA (verified r9): lane holds row=wr+m*16+(lane&15),
// cols=wc+n*16+(lane>>4)*4+{0..3}.
// MODE 0: +bias -> bf16 Y + column sum/sumsq atomics
// MODE 1: +bias, relu, f32 out       MODE 2: +bias, f32 out
template<int K, int NC, int MODE>
__global__ __launch_bounds__(256) void k_gemm(
    const unsigned short* __restrict__ A, const unsigned short* __restrict__ Bt,
    const float* __restrict__ bias, unsigned short* __restrict__ Ybf,
    float* __restrict__ Hout, float* __restrict__ colsum, float* __restrict__ colsq) {
  constexpr int KT = K / 32;
  constexpr int NCB = NC / 128;
  __shared__ __align__(16) unsigned short lA[2][128 * 32];
  __shared__ __align__(16) unsigned short lB[2][128 * 32];

  // XCD-aware decode: x = b%8 (XCD), q = b/8; col fastest, row = x + 8*(q/NCB)
  int b = blockIdx.x;
  int q = b >> 3;
  int colb = q % NCB;
  int rowb = (b & 7) + 8 * (q / NCB);
  if (rowb * 128 >= NN) return;
  const int row0 = rowb * 128, col0 = colb * 128;

  const int tid = threadIdx.x;
  const int lane = tid & 63, wave = tid >> 6;
  const int lr = lane & 15, lg = lane >> 4;
  const int wr = (wave >> 1) * 64, wc = (wave & 1) * 64;

  // staging addresses: wave w stages rows w*32..w*32+31 of both tiles.
  // chunk = 16 rows = 64 lanes x 16B; lane l -> row +(l>>2), k-off (l&3)*8
  int aR0 = row0 + wave * 32 + (lane >> 2);
  int aR1 = aR0 + 16;
  if (aR0 > NN - 1) aR0 = NN - 1;
  if (aR1 > NN - 1) aR1 = NN - 1;
  const int kc = (lane & 3) * 8;
  const unsigned short* aS0 = A + (size_t)aR0 * K + kc;
  const unsigned short* aS1 = A + (size_t)aR1 * K + kc;
  const unsigned short* bS0 = Bt + (size_t)(col0 + wave * 32 + (lane >> 2)) * K + kc;
  const unsigned short* bS1 = bS0 + (size_t)16 * K;

  f32x4 acc[4][4] = {};

  auto stage = [&](int buf, int kt) {
    int ko = kt * 32;
    gload_lds16(aS0 + ko, &lA[buf][wave * 1024]);
    gload_lds16(aS1 + ko, &lA[buf][wave * 1024 + 512]);
    gload_lds16(bS0 + ko, &lB[buf][wave * 1024]);
    gload_lds16(bS1 + ko, &lB[buf][wave * 1024 + 512]);
  };

  stage(0, 0);
  __syncthreads();                 // vmcnt(0) drain -> buf0 ready
  int buf = 0;
  for (int kt = 0; kt < KT; ++kt) {
    if (kt + 1 < KT) stage(buf ^ 1, kt + 1);   // async, in flight across compute
    bf16x8 af[4], bfr[4];
#pragma unroll
    for (int m = 0; m < 4; ++m)
      af[m] = *(const bf16x8*)&lA[buf][(wr + m * 16 + lr) * 32 + lg * 8];
#pragma unroll
    for (int n = 0; n < 4; ++n)
      bfr[n] = *(const bf16x8*)&lB[buf][(wc + n * 16 + lr) * 32 + lg * 8];
#pragma unroll
    for (int m = 0; m < 4; ++m)
#pragma unroll
      for (int n = 0; n < 4; ++n)
        acc[m][n] = __builtin_amdgcn_mfma_f32_16x16x32_bf16(bfr[n], af[m], acc[m][n], 0, 0, 0);
    __syncthreads();               // drains staging vmcnt + frag lgkm; buf^1 ready
    buf ^= 1;
  }

  if constexpr (MODE == 0) {
    f32x4 csum[4] = {}, csq[4] = {};
#pragma unroll
    for (int n = 0; n < 4; ++n) {
      const int gcB = col0 + wc + n * 16 + lg * 4;
      f32x4 bv = *(const f32x4*)&bias[gcB];
#pragma unroll
      for (int m = 0; m < 4; ++m) {
        int gr = row0 + wr + m * 16 + lr;
        if (gr < NN) {
          f32x4 v = acc[m][n] + bv;
          u16x4 o;
#pragma unroll
          for (int j = 0; j < 4; ++j) o[j] = f2bf(v[j]);
          *(u16x4*)&Ybf[(size_t)gr * NC + gcB] = o;
          csum[n] += v;
          csq[n] += v * v;
        }
      }
    }
#pragma unroll
    for (int n = 0; n < 4; ++n)
#pragma unroll
      for (int j = 0; j < 4; ++j) {
        float s = csum[n][j], qq = csq[n][j];
        s += __shfl_xor(s, 1, 64); qq += __shfl_xor(qq, 1, 64);
        s += __shfl_xor(s, 2, 64); qq += __shfl_xor(qq, 2, 64);
        s += __shfl_xor(s, 4, 64); qq += __shfl_xor(qq, 4, 64);
        s += __shfl_xor(s, 8, 64); qq += __shfl_xor(qq, 8, 64);
        if (lr == 0) {
          atomicAdd(&colsum[col0 + wc + n * 16 + lg * 4 + j], s);
          atomicAdd(&colsq[col0 + wc + n * 16 + lg * 4 + j], qq);
        }
      }
  } else {
#pragma unroll
    for (int n = 0; n < 4; ++n) {
      const int gcB = col0 + wc + n * 16 + lg * 4;
      f32x4 bv = *(const f32x4*)&bias[gcB];
#pragma unroll
      for (int m = 0; m < 4; ++m) {
        int gr = row0 + wr + m * 16 + lr;
        if (gr < NN) {
          f32x4 v = acc[m][n] + bv;
          if constexpr (MODE == 1) {
#pragma unroll
            for (int j = 0; j < 4; ++j) v[j] = fmaxf(v[j], 0.f);
          }
          *(f32x4*)&Hout[(size_t)gr * NC + gcB] = v;
        }
      }
    }
  }
}

// ---------------- BN finalize ----------------
__global__ void k_bnfin(const float* __restrict__ colsum, const float* __restrict__ colsq,
    const float* __restrict__ gamma, const float* __restrict__ beta,
    float* __restrict__ scale, float* __restrict__ shift) {
  int c = threadIdx.x;
  float inv_n = 1.0f / (float)NN;
  float mu = colsum[c] * inv_n;
  float var = colsq[c] * inv_n - mu * mu;
  float rstd = rsqrtf(var + 1e-5f);
  float sc = rstd * gamma[c];
  scale[c] = sc;
  shift[c] = beta[c] - mu * sc;
}

// ---------------- BN apply (in place on y): y = relu(y*scale[c]+shift[c]) ----------------
__global__ __launch_bounds__(256) void k_bnapply(unsigned short* __restrict__ y,
    const float* __restrict__ scale, const float* __restrict__ shift) {
  const int total = NN * (HID / 8);
  for (int idx = blockIdx.x * 256 + threadIdx.x; idx < total; idx += gridDim.x * 256) {
    int c8 = (idx & (HID / 8 - 1)) * 8;
    U8u a; a.v = *(const u16x8*)&y[(size_t)idx * 8];
    f32x4 s0 = *(const f32x4*)&scale[c8], s1 = *(const f32x4*)&scale[c8 + 4];
    f32x4 t0 = *(const f32x4*)&shift[c8], t1 = *(const f32x4*)&shift[c8 + 4];
    U8u o;
#pragma unroll
    for (int j = 0; j < 4; ++j) {
      o.s[j]     = f2bf(fmaxf(bf2f(a.s[j])     * s0[j] + t0[j], 0.f));
      o.s[4 + j] = f2bf(fmaxf(bf2f(a.s[4 + j]) * s1[j] + t1[j], 0.f));
    }
    *(u16x8*)&y[(size_t)idx * 8] = o.v;
  }
}

extern "C" void kernel_launch(void* const* d_in, const int* in_sizes, int n_in,
                              void* d_out, int out_size, void* d_ws, size_t ws_size,
                              hipStream_t stream) {
  (void)in_sizes; (void)n_in; (void)out_size; (void)ws_size;
  const int* node_ids    = (const int*)d_in[0];
  const int* node_depth  = (const int*)d_in[1];
  const int* edge_index  = (const int*)d_in[2];
  const float* edge_attr = (const float*)d_in[3];
  const float* temb      = (const float*)d_in[4];
  const float* demb      = (const float*)d_in[5];
  const float* We        = (const float*)d_in[6];
  const float* be        = (const float*)d_in[7];
  const float* W1        = (const float*)d_in[8];
  const float* b1        = (const float*)d_in[9];
  const float* gamma_    = (const float*)d_in[10];
  const float* beta_     = (const float*)d_in[11];
  const float* W2        = (const float*)d_in[12];
  const float* b2        = (const float*)d_in[13];
  const float* epsp      = (const float*)d_in[14];
  float* h = (float*)d_out;

  char* ws = (char*)d_ws;
  size_t off = 0;
  auto alloc = [&](size_t bytes) -> void* {
    void* p = ws + off;
    off = (off + bytes + 255) & ~(size_t)255;
    return p;
  };
  unsigned short* z   = (unsigned short*)alloc(2ull * NN * EMB);        // 25.6 MB
  unsigned short* y   = (unsigned short*)alloc(2ull * NN * HID);        // 51.2 MB
  unsigned short* W1t = (unsigned short*)alloc(2ull * NL * EMB * HID);  // 1.3 MB
  unsigned short* W2t = (unsigned short*)alloc(2ull * NL * HID * EMB);  // 1.3 MB
  int* deg      = (int*)alloc(sizeof(int) * NN);
  int* row_off  = (int*)alloc(sizeof(int) * (NN + 1));
  int* cursor   = (int*)alloc(sizeof(int) * NN);
  int* ssrc     = (int*)alloc(sizeof(int) * NE);
  float2* sattr = (float2*)alloc(sizeof(float2) * NE);
  int* bsums    = (int*)alloc(sizeof(int) * 256);
  float* colsum = (float*)alloc(sizeof(float) * HID * 2);
  float* colsq  = colsum + HID;
  float* scale  = (float*)alloc(sizeof(float) * HID);
  float* shift  = (float*)alloc(sizeof(float) * HID);

  const int* e_src = edge_index;
  const int* e_dst = edge_index + NE;

  k_init_h<<<(NN * 64) / 256, 256, 0, stream>>>(node_ids, node_depth, temb, demb, h);
  hipMemsetAsync(deg, 0, sizeof(int) * NN, stream);
  k_count<<<(NE + 255) / 256, 256, 0, stream>>>(e_dst, deg);
  k_scan1<<<49, 256, 0, stream>>>(deg, row_off, bsums);
  k_scan2<<<1, 256, 0, stream>>>(bsums, 49);
  k_scan3<<<49, 256, 0, stream>>>(row_off, bsums);
  k_copy<<<(NN + 255) / 256, 256, 0, stream>>>(row_off, cursor);
  k_fill<<<(NE + 255) / 256, 256, 0, stream>>>(e_src, e_dst, edge_attr, cursor, ssrc, sattr);
  // weights: W1 [L][EMB][HID] -> W1t [L][HID][EMB]; W2 [L][HID][EMB] -> W2t [L][EMB][HID]
  k_convW<<<dim3(HID / 32, EMB / 32, NL), 256, 0, stream>>>(W1, W1t, EMB, HID);
  k_convW<<<dim3(EMB / 32, HID / 32, NL), 256, 0, stream>>>(W2, W2t, HID, EMB);

  const int MB = (NN + 127) / 128;          // 391 row-blocks
  const int RG8 = (MB + 7) / 8;             // row-groups per XCD (49)
  const int G1 = 8 * (HID / 128) * RG8;     // 1568 blocks (some idle-return)
  const int G2 = 8 * (EMB / 128) * RG8;     // 784 blocks
  for (int l = 0; l < NL; ++l) {
    k_aggregate<<<(NN * 64) / 256, 256, 0, stream>>>(
        h, row_off, ssrc, sattr, We + (size_t)l * 2 * EMB, be + (size_t)l * EMB, epsp, l, z);
    hipMemsetAsync(colsum, 0, sizeof(float) * HID * 2, stream);
    // GEMM1: y = z @ W1 + b1 (bf16 out) + column stats
    k_gemm<EMB, HID, 0><<<G1, 256, 0, stream>>>(
        z, W1t + (size_t)l * EMB * HID, b1 + (size_t)l * HID, y, nullptr, colsum, colsq);
    k_bnfin<<<1, HID, 0, stream>>>(colsum, colsq, gamma_ + (size_t)l * HID,
                                   beta_ + (size_t)l * HID, scale, shift);
    // BN + ReLU applied in place on y (bf16), then pure GEMM2
    k_bnapply<<<2048, 256, 0, stream>>>(y, scale, shift);
    if (l < NL - 1)
      k_gemm<HID, EMB, 1><<<G2, 256, 0, stream>>>(
          y, W2t + (size_t)l * HID * EMB, b2 + (size_t)l * EMB, nullptr, h, nullptr, nullptr);
    else
      k_gemm<HID, EMB, 2><<<G2, 256, 0, stream>>>(
          y, W2t + (size_t)l * HID * EMB, b2 + (size_t)l * EMB, nullptr, h, nullptr, nullptr);
  }
}